// Round 1
// baseline (88.386 us; speedup 1.0000x reference)
//
#include <hip/hip_runtime.h>

// Geometry (fixed by the problem)
#define BATCH 8
#define PNUM 32            // 32x32 patch grid
#define PTOT (PNUM*PNUM)   // 1024 patches per image
#define GPP 32             // gaussians per patch
#define PSZ 16             // patch is 16x16 pixels
#define IMG 512            // 512x512 image
#define PATCHES_PER_BLOCK 4

static __device__ __forceinline__ float fast_sigmoid(float x) {
    const float L2E = 1.4426950408889634f;
    return __builtin_amdgcn_rcpf(1.0f + __builtin_amdgcn_exp2f(-L2E * x));
}

__global__ __launch_bounds__(256) void splat_kernel(
    const float* __restrict__ xyz,      // [B,P,G,2]
    const float* __restrict__ chol,     // [B,P,G,3]
    const float* __restrict__ color,    // [B,P,G,3]
    const float* __restrict__ opacity,  // [B,P,G,1]
    float* __restrict__ out)            // [B,3,512,512]
{
    const float L2E = 1.4426950408889634f;

    // Per-gaussian derived params, 2 x float4 each:
    //  gA = (mean_x, mean_y, ca' = -0.5*L2E*ca, cb2 = -L2E*cb)
    //  gB = (cc' = -0.5*L2E*cc, op*r, op*g, op*b)
    __shared__ float4 gA[PATCHES_PER_BLOCK][GPP];
    __shared__ float4 gB[PATCHES_PER_BLOCK][GPP];

    const int tid = threadIdx.x;

    // ---- Phase 1: prep (128 threads, one gaussian each) ----
    if (tid < PATCHES_PER_BLOCK * GPP) {
        const int w  = tid >> 5;          // patch-in-block
        const int g  = tid & 31;
        const int bp = blockIdx.x * PATCHES_PER_BLOCK + w;  // global (b*P+p)
        const int gi = bp * GPP + g;

        const float x0 = xyz[gi*2+0], x1 = xyz[gi*2+1];
        const float c0 = chol[gi*3+0], c1 = chol[gi*3+1], c2 = chol[gi*3+2];
        const float r0 = color[gi*3+0], r1 = color[gi*3+1], r2 = color[gi*3+2];
        const float op = opacity[gi];

        const float mx = 16.0f * fast_sigmoid(x0);
        const float my = 16.0f * fast_sigmoid(x1);

        const float l0 = fabsf(c0) + 0.5f;
        const float l1 = c1;
        const float l2 = fabsf(c2) + 0.5f;
        const float s00 = l0*l0;
        const float s01 = l0*l1;
        const float s11 = l1*l1 + l2*l2;
        const float det = s00*s11 - s01*s01;     // = l0^2*l2^2 >= 1/16, safe
        const float idet = __builtin_amdgcn_rcpf(det);

        // power*log2(e) = cap*dx^2 + ccp*dy^2 + cb2*dx*dy
        const float cap = -0.5f * L2E * s11 * idet;
        const float ccp = -0.5f * L2E * s00 * idet;
        const float cb2 =         L2E * s01 * idet;

        const float so = fast_sigmoid(op);

        gA[w][g] = make_float4(mx, my, cap, cb2);
        gB[w][g] = make_float4(ccp, so*r0, so*r1, so*r2);
    }
    __syncthreads();

    // ---- Phase 2: rasterize. One wave per patch; each lane: 1 column pos x 4 rows ----
    const int w    = tid >> 6;      // wave id == patch-in-block
    const int lane = tid & 63;
    const float px  = (float)(lane & 15) + 0.5f;
    const float py0 = (float)(lane >> 4) + 0.5f;   // rows py0, py0+4, py0+8, py0+12

    float aR[4], aG[4], aB[4];
    #pragma unroll
    for (int k = 0; k < 4; ++k) { aR[k] = 0.f; aG[k] = 0.f; aB[k] = 0.f; }

    #pragma unroll 4
    for (int g = 0; g < GPP; ++g) {
        const float4 A  = gA[w][g];   // wave-uniform ds_read_b128 (broadcast)
        const float4 Bv = gB[w][g];
        const float dx = px - A.x;
        const float t  = A.w * dx;          // cb2*dx
        const float pb = A.z * dx * dx;     // cap*dx^2
        #pragma unroll
        for (int k = 0; k < 4; ++k) {
            const float dy = (py0 + 4.0f*(float)k) - A.y;
            float p = fmaf(Bv.x, dy*dy, pb);
            p = fmaf(t, dy, p);
            p = fminf(p, 0.0f);
            const float wg = __builtin_amdgcn_exp2f(p);
            aR[k] = fmaf(wg, Bv.y, aR[k]);
            aG[k] = fmaf(wg, Bv.z, aG[k]);
            aB[k] = fmaf(wg, Bv.w, aB[k]);
        }
    }

    // ---- Write out: [B,3,512,512], row = pn0*16+py, col = pn1*16+px ----
    const int bp  = blockIdx.x * PATCHES_PER_BLOCK + w;
    const int b   = bp >> 10;        // / 1024
    const int p   = bp & 1023;
    const int pn0 = p >> 5, pn1 = p & 31;
    const int X     = pn1 * PSZ + (lane & 15);
    const int Ybase = pn0 * PSZ + (lane >> 4);
    const size_t obase = (size_t)b * 3 * IMG * IMG;
    #pragma unroll
    for (int k = 0; k < 4; ++k) {
        const size_t idx = obase + (size_t)(Ybase + 4*k) * IMG + X;
        out[idx]                       = aR[k];
        out[idx + (size_t)IMG*IMG]     = aG[k];
        out[idx + (size_t)2*IMG*IMG]   = aB[k];
    }
}

extern "C" void kernel_launch(void* const* d_in, const int* in_sizes, int n_in,
                              void* d_out, int out_size, void* d_ws, size_t ws_size,
                              hipStream_t stream) {
    const float* xyz     = (const float*)d_in[0];
    const float* chol    = (const float*)d_in[1];
    const float* color   = (const float*)d_in[2];
    const float* opacity = (const float*)d_in[3];
    float* out = (float*)d_out;

    const int nblocks = (BATCH * PTOT) / PATCHES_PER_BLOCK;  // 2048
    splat_kernel<<<nblocks, 256, 0, stream>>>(xyz, chol, color, opacity, out);
}

// Round 2
// 85.556 us; speedup vs baseline: 1.0331x; 1.0331x over previous
//
#include <hip/hip_runtime.h>

// Geometry (fixed by the problem)
#define BATCH 8
#define PNUM 32            // 32x32 patch grid
#define PTOT (PNUM*PNUM)   // 1024 patches per image
#define GPP 32             // gaussians per patch
#define PSZ 16             // patch is 16x16 pixels
#define IMG 512            // 512x512 image
#define PATCHES_PER_BLOCK 4

static __device__ __forceinline__ float fast_sigmoid(float x) {
    const float L2E = 1.4426950408889634f;
    return __builtin_amdgcn_rcpf(1.0f + __builtin_amdgcn_exp2f(-L2E * x));
}

__global__ __launch_bounds__(256) void splat_kernel(
    const float* __restrict__ xyz,      // [B,P,G,2]
    const float* __restrict__ chol,     // [B,P,G,3]
    const float* __restrict__ color,    // [B,P,G,3]
    const float* __restrict__ opacity,  // [B,P,G,1]
    float* __restrict__ out)            // [B,3,512,512]
{
    const float L2E = 1.4426950408889634f;

    // Per-gaussian derived params, 2 x float4 each:
    //  gA = (mean_x, mean_y, cap = -0.5*L2E*ca, cb2 = -L2E*cb)
    //  gB = (ccp = -0.5*L2E*cc, op*r, op*g, op*b)
    __shared__ float4 gA[PATCHES_PER_BLOCK][GPP];
    __shared__ float4 gB[PATCHES_PER_BLOCK][GPP];

    const int tid = threadIdx.x;

    // ---- Phase 1: prep (128 threads, one gaussian each) ----
    if (tid < PATCHES_PER_BLOCK * GPP) {
        const int w  = tid >> 5;          // patch-in-block
        const int g  = tid & 31;
        const int bp = blockIdx.x * PATCHES_PER_BLOCK + w;  // global (b*P+p)
        const int gi = bp * GPP + g;

        const float2 x01 = ((const float2*)xyz)[gi];
        const float c0 = chol[gi*3+0], c1 = chol[gi*3+1], c2 = chol[gi*3+2];
        const float r0 = color[gi*3+0], r1 = color[gi*3+1], r2 = color[gi*3+2];
        const float op = opacity[gi];

        const float mx = 16.0f * fast_sigmoid(x01.x);
        const float my = 16.0f * fast_sigmoid(x01.y);

        const float l0 = fabsf(c0) + 0.5f;
        const float l1 = c1;
        const float l2 = fabsf(c2) + 0.5f;
        const float s00 = l0*l0;
        const float s01 = l0*l1;
        const float s11 = l1*l1 + l2*l2;
        const float det = s00*s11 - s01*s01;     // = l0^2*l2^2 >= 1/16, safe
        const float idet = __builtin_amdgcn_rcpf(det);

        // power*log2(e) = cap*dx^2 + ccp*dy^2 + cb2*dx*dy
        const float cap = -0.5f * L2E * s11 * idet;
        const float ccp = -0.5f * L2E * s00 * idet;
        const float cb2 =         L2E * s01 * idet;

        const float so = fast_sigmoid(op);

        gA[w][g] = make_float4(mx, my, cap, cb2);
        gB[w][g] = make_float4(ccp, so*r0, so*r1, so*r2);
    }
    __syncthreads();

    // ---- Phase 2: rasterize. One wave per patch.
    // Lane l owns row = l>>2, columns 4*(l&3) .. +3  (4 consecutive pixels).
    const int w    = tid >> 6;
    const int lane = tid & 63;
    const int row  = lane >> 2;
    const int col0 = (lane & 3) << 2;
    const float fy  = (float)row + 0.5f;
    const float fx0 = (float)col0 + 0.5f;

    float aR[4], aG[4], aB[4];
    #pragma unroll
    for (int j = 0; j < 4; ++j) { aR[j] = 0.f; aG[j] = 0.f; aB[j] = 0.f; }

    #pragma unroll 4
    for (int g = 0; g < GPP; ++g) {
        const float4 A  = gA[w][g];   // wave-uniform ds_read_b128 (broadcast)
        const float4 Bv = gB[w][g];
        const float dy  = fy - A.y;
        const float tdy = A.w * dy;          // cb2*dy
        const float ey  = (Bv.x * dy) * dy;  // ccp*dy^2
        #pragma unroll
        for (int j = 0; j < 4; ++j) {
            const float dx = (fx0 + (float)j) - A.x;
            float p = fmaf(dx, fmaf(A.z, dx, tdy), ey);  // cap*dx^2 + cb2*dx*dy + ccp*dy^2
            p = fminf(p, 0.0f);
            const float wg = __builtin_amdgcn_exp2f(p);
            aR[j] = fmaf(wg, Bv.y, aR[j]);
            aG[j] = fmaf(wg, Bv.z, aG[j]);
            aB[j] = fmaf(wg, Bv.w, aB[j]);
        }
    }

    // ---- Write out: [B,3,512,512]; lane writes one float4 per channel ----
    const int bp  = blockIdx.x * PATCHES_PER_BLOCK + w;
    const int b   = bp >> 10;        // / 1024
    const int p   = bp & 1023;
    const int pn0 = p >> 5, pn1 = p & 31;
    const int X   = pn1 * PSZ + col0;
    const int Y   = pn0 * PSZ + row;
    float* o = out + (size_t)b * 3 * IMG * IMG + (size_t)Y * IMG + X;

    *(float4*)(o)                         = make_float4(aR[0], aR[1], aR[2], aR[3]);
    *(float4*)(o + (size_t)IMG*IMG)       = make_float4(aG[0], aG[1], aG[2], aG[3]);
    *(float4*)(o + (size_t)2*IMG*IMG)     = make_float4(aB[0], aB[1], aB[2], aB[3]);
}

extern "C" void kernel_launch(void* const* d_in, const int* in_sizes, int n_in,
                              void* d_out, int out_size, void* d_ws, size_t ws_size,
                              hipStream_t stream) {
    const float* xyz     = (const float*)d_in[0];
    const float* chol    = (const float*)d_in[1];
    const float* color   = (const float*)d_in[2];
    const float* opacity = (const float*)d_in[3];
    float* out = (float*)d_out;

    const int nblocks = (BATCH * PTOT) / PATCHES_PER_BLOCK;  // 2048
    splat_kernel<<<nblocks, 256, 0, stream>>>(xyz, chol, color, opacity, out);
}